// Round 2
// baseline (4401.440 us; speedup 1.0000x reference)
//
#include <hip/hip_runtime.h>

#define TPB 256
#define CHUNK 16

__global__ __launch_bounds__(TPB) void sudoku_kernel(
    const float* __restrict__ x_in,
    const float* __restrict__ W1,
    const float* __restrict__ W2,
    float* __restrict__ out)
{
    const int b = blockIdx.x;
    const int t = threadIdx.x;

    __shared__ float  xs[729];
    __shared__ float  xp[729];
    __shared__ float  cnt[27 * 12];
    __shared__ float  W1L[100 * 29];     // W1[j][f] at W1L[j*29+f]
    __shared__ float  W2T[100 * 12];     // W2[v][j] at W2T[j*12+v]
    __shared__ double H1[27 * 101];      // per-group partial hidden (f64)
    __shared__ double hbuf[CHUNK * 101]; // relu hidden (f64)
    __shared__ double ybuf[CHUNK * 12];
    __shared__ double score_l[81];
    __shared__ int    pos_l[81];
    __shared__ int    elist[81];
    __shared__ int    sh_ne;

    const float* xb = x_in + (size_t)b * 729;
    for (int i = t; i < 729; i += TPB) { float v = xb[i]; xs[i] = v; xp[i] = v; }
    for (int i = t; i < 2700; i += TPB) { int j = i / 27, f = i - 27 * j; W1L[j * 29 + f] = W1[i]; }
    for (int i = t; i < 900; i += TPB) { int v = i / 100, j = i - 100 * v; W2T[j * 12 + v] = W2[i]; }
    __syncthreads();

    // initial empty list (ascending cell order = np first-index tie-break)
    if (t == 0) {
        int ne = 0;
        for (int c = 0; c < 81; c++) {
            float s = 0.f;
            #pragma unroll
            for (int v = 0; v < 9; v++) s += xs[c * 9 + v];
            if (s == 0.f) elist[ne++] = c;
        }
        sh_ne = ne;
    }
    __syncthreads();
    int ne = sh_ne;

    while (ne > 0) {
        // P1: group counts (sums of 0/1 -> exact in f32)
        for (int o = t; o < 243; o += TPB) {
            int g = o / 9, v = o - 9 * g;
            float s = 0.f;
            if (g < 9) {
                int base = g * 9;
                #pragma unroll
                for (int k = 0; k < 9; k++) s += xs[(base + k) * 9 + v];
            } else if (g < 18) {
                int c = g - 9;
                #pragma unroll
                for (int k = 0; k < 9; k++) s += xs[(c + 9 * k) * 9 + v];
            } else {
                int bx = g - 18;
                int base = (bx / 3) * 27 + (bx % 3) * 3;
                #pragma unroll
                for (int k = 0; k < 9; k++) s += xs[(base + (k / 3) * 9 + (k % 3)) * 9 + v];
            }
            cnt[g * 12 + v] = s;
        }
        __syncthreads();

        // P2: H1[g][j] = sum_v W1[j][type*9+v] * cnt[g][v]   (f64)
        for (int o = t; o < 2700; o += TPB) {
            int g = o / 100, j = o - 100 * g;
            int type = (g >= 18) ? 2 : (g >= 9 ? 1 : 0);
            const float* w = &W1L[j * 29 + type * 9];
            const float* c = &cnt[g * 12];
            double s = 0.0;
            #pragma unroll
            for (int v = 0; v < 9; v++) s += (double)w[v] * (double)c[v];
            H1[g * 101 + j] = s;
        }
        __syncthreads();

        // MLP + softmax only for empty cells, in chunks
        for (int c0 = 0; c0 < ne; c0 += CHUNK) {
            int cn = min(CHUNK, ne - c0);
            // P3: hidden = relu(H1[row]+H1[col]+H1[box])   (f64)
            for (int o = t; o < cn * 100; o += TPB) {
                int e = o / 100, j = o - 100 * e;
                int cell = elist[c0 + e];
                int r = cell / 9, cc = cell - 9 * r;
                int bx = (r / 3) * 3 + cc / 3;
                double g = H1[r * 101 + j] + H1[(9 + cc) * 101 + j] + H1[(18 + bx) * 101 + j];
                hbuf[e * 101 + j] = g > 0.0 ? g : 0.0;
            }
            __syncthreads();
            // P4: y[e][v] = h[e]·W2[v]   (f64, 2 accumulators)
            for (int o = t; o < cn * 9; o += TPB) {
                int e = o / 9, v = o - 9 * e;
                const double* hh = &hbuf[e * 101];
                double s0 = 0.0, s1 = 0.0;
                #pragma unroll
                for (int j = 0; j < 100; j += 2) {
                    s0 += hh[j + 0] * (double)W2T[(j + 0) * 12 + v];
                    s1 += hh[j + 1] * (double)W2T[(j + 1) * 12 + v];
                }
                ybuf[e * 12 + v] = s0 + s1;
            }
            __syncthreads();
            // P5: softmax (f64), score, pos, x_pred update
            for (int e = t; e < cn; e += TPB) {
                int cell = elist[c0 + e];
                double m = ybuf[e * 12];
                #pragma unroll
                for (int v = 1; v < 9; v++) m = fmax(m, ybuf[e * 12 + v]);
                double p[9]; double s = 0.0;
                #pragma unroll
                for (int v = 0; v < 9; v++) { p[v] = exp(ybuf[e * 12 + v] - m); s += p[v]; }
                double inv = 1.0 / s;
                double best = -1.0; int bv = 0;
                #pragma unroll
                for (int v = 0; v < 9; v++) {
                    double pr = p[v] * inv;
                    xp[cell * 9 + v] = (float)pr;
                    if (pr > best) { best = pr; bv = v; }  // strict > = first-index tie-break
                }
                score_l[c0 + e] = best;
                pos_l[c0 + e] = bv;
            }
            __syncthreads();
        }

        // P6: argmax over empty cells (elist ascending -> np argmax tie-break),
        // fill the chosen cell, drop it from the list
        if (t == 0) {
            double best = score_l[0]; int be = 0;
            for (int e = 1; e < ne; e++) if (score_l[e] > best) { best = score_l[e]; be = e; }
            int cell = elist[be];
            xs[cell * 9 + pos_l[be]] = 1.0f;
            for (int e = be; e < ne - 1; e++) elist[e] = elist[e + 1];
            sh_ne = ne - 1;
        }
        __syncthreads();
        ne = sh_ne;
    }

    float* outp = out + (size_t)b * 729;
    float* outx = out + (size_t)4096 * 729 + (size_t)b * 729;
    for (int i = t; i < 729; i += TPB) { outp[i] = xp[i]; outx[i] = xs[i]; }
}

extern "C" void kernel_launch(void* const* d_in, const int* in_sizes, int n_in,
                              void* d_out, int out_size, void* d_ws, size_t ws_size,
                              hipStream_t stream) {
    const float* x  = (const float*)d_in[0];
    const float* W1 = (const float*)d_in[1];
    const float* W2 = (const float*)d_in[2];
    (void)in_sizes; (void)n_in; (void)out_size; (void)d_ws; (void)ws_size;
    sudoku_kernel<<<4096, TPB, 0, stream>>>(x, W1, W2, (float*)d_out);
}

// Round 3
// 1318.973 us; speedup vs baseline: 3.3370x; 3.3370x over previous
//
#include <hip/hip_runtime.h>

#define TPB 256

// y for a cell is a deterministic function of its (row,col,box) count triple:
// H1 rows are always recomputed freshly in canonical v-order, hidden/y/softmax
// use one fixed f64 summation structure everywhere. Equal count-triples give
// bit-identical scores -> np first-index tie-breaks are reproduced by strict->
// comparisons in index order.

__device__ __forceinline__ void fused_partial(
    int cell, int q, int slot,
    const double* __restrict__ H1, const float* __restrict__ W2T,
    double* __restrict__ pbuf)
{
    int r = cell / 9, c = cell - 9 * r;
    int bx = (r / 3) * 3 + c / 3;
    const double* Hr = H1 + r * 101;
    const double* Hc = H1 + (9 + c) * 101;
    const double* Hb = H1 + (18 + bx) * 101;
    double acc[9];
#pragma unroll
    for (int v = 0; v < 9; v++) acc[v] = 0.0;
    const int j0 = q * 20;
#pragma unroll 2
    for (int jj = 0; jj < 20; jj++) {
        int j = j0 + jj;
        double h = Hr[j] + Hc[j] + Hb[j];
        h = h > 0.0 ? h : 0.0;
        const float* w = W2T + j * 12;
#pragma unroll
        for (int v = 0; v < 9; v++) acc[v] = fma(h, (double)w[v], acc[v]);
    }
    double* pb = pbuf + (slot * 5 + q) * 9;
#pragma unroll
    for (int v = 0; v < 9; v++) pb[v] = acc[v];
}

__device__ __forceinline__ void combine_softmax(
    int cell, int slot,
    const double* __restrict__ pbuf,
    float* __restrict__ outp,
    double* __restrict__ score_l, int* __restrict__ pos_l)
{
    double y[9];
#pragma unroll
    for (int v = 0; v < 9; v++) {
        double s = 0.0;
#pragma unroll
        for (int q = 0; q < 5; q++) s += pbuf[(slot * 5 + q) * 9 + v];
        y[v] = s;
    }
    double m = y[0];
#pragma unroll
    for (int v = 1; v < 9; v++) m = fmax(m, y[v]);
    double p[9], sum = 0.0;
#pragma unroll
    for (int v = 0; v < 9; v++) { p[v] = exp(y[v] - m); sum += p[v]; }
    double inv = 1.0 / sum;
    double best = -1.0; int bv = 0;
#pragma unroll
    for (int v = 0; v < 9; v++) {
        double pr = p[v] * inv;
        outp[cell * 9 + v] = (float)pr;
        if (pr > best) { best = pr; bv = v; }   // strict > : first-index tie-break
    }
    score_l[cell] = best;
    pos_l[cell] = bv;
}

__device__ __forceinline__ int affected_cell(int slot, int fr, int fc) {
    if (slot < 9)  return fr * 9 + slot;            // row
    if (slot < 18) return (slot - 9) * 9 + fc;      // col
    int r0 = (fr / 3) * 3, c0 = (fc / 3) * 3;       // box cells off-row/off-col
    int dr = fr - r0, dc = fc - c0;
    int rA = r0 + (dr == 0 ? 1 : 0), rB = r0 + (dr == 2 ? 1 : 2);
    int cA = c0 + (dc == 0 ? 1 : 0), cB = c0 + (dc == 2 ? 1 : 2);
    int k = slot - 18;
    return ((k < 2) ? rA : rB) * 9 + ((k & 1) ? cB : cA);
}

__global__ __launch_bounds__(TPB, 4) void sudoku_kernel(
    const float* __restrict__ x_in,
    const float* __restrict__ W1,
    const float* __restrict__ W2,
    float* __restrict__ out,
    int nb)
{
    const int b = blockIdx.x;
    const int t = threadIdx.x;

    __shared__ float  xs[729];
    __shared__ float  W2T[100 * 12];   // W2T[j*12+v] = W2[v][j]
    __shared__ float  cnt[27 * 12];    // exact small ints in f32
    __shared__ double H1[27 * 101];    // H1[g][j] = sum_v W1[j][type*9+v]*cnt[g][v]
    __shared__ double pbuf[22 * 5 * 9];
    __shared__ double score_l[81];     // cached score; -1 = filled
    __shared__ int    pos_l[81];
    __shared__ double red_s[2];
    __shared__ int    red_i[2];
    __shared__ int    bc_cell;

    float* outp = out + (size_t)b * 729;
    float* outx = out + (size_t)nb * 729 + (size_t)b * 729;
    const float* xb = x_in + (size_t)b * 729;

    for (int i = t; i < 729; i += TPB) { float v = xb[i]; xs[i] = v; outp[i] = v; }
    for (int i = t; i < 900; i += TPB) { int v = i / 100, j = i - 100 * v; W2T[j * 12 + v] = W2[i]; }
    __syncthreads();

    // empty flags (score placeholder 0.0) + initial counts
    if (t < 81) {
        float s = 0.f;
#pragma unroll
        for (int v = 0; v < 9; v++) s += xs[t * 9 + v];
        score_l[t] = (s == 0.f) ? 0.0 : -1.0;
        pos_l[t] = 0;
    }
    for (int o = t; o < 243; o += TPB) {
        int g = o / 9, v = o - 9 * g;
        float s = 0.f;
        if (g < 9) {
            int base = g * 9;
#pragma unroll
            for (int k = 0; k < 9; k++) s += xs[(base + k) * 9 + v];
        } else if (g < 18) {
            int c = g - 9;
#pragma unroll
            for (int k = 0; k < 9; k++) s += xs[(c + 9 * k) * 9 + v];
        } else {
            int bx = g - 18;
            int base = (bx / 3) * 27 + (bx % 3) * 3;
#pragma unroll
            for (int k = 0; k < 9; k++) s += xs[(base + (k / 3) * 9 + (k % 3)) * 9 + v];
        }
        cnt[g * 12 + v] = s;
    }
    __syncthreads();

    // full H1 init (canonical v-order, W1 read from global/L1)
    for (int o = t; o < 2700; o += TPB) {
        int g = o / 100, j = o - 100 * g;
        int type = (g >= 18) ? 2 : (g >= 9 ? 1 : 0);
        const float* w = W1 + j * 27 + type * 9;
        const float* cc = cnt + g * 12;
        double s = 0.0;
#pragma unroll
        for (int v = 0; v < 9; v++) s = fma((double)w[v], (double)cc[v], s);
        H1[g * 101 + j] = s;
    }
    int myflag = (t < 81) ? (score_l[t] == 0.0) : 0;
    int ne = __syncthreads_count(myflag);   // barrier: H1 visible after this

    // initial probs/scores for all empty cells, 22-cell chunks
    for (int c0 = 0; c0 < 81; c0 += 22) {
        int slot = t % 22, q = t / 22;
        if (q < 5) {
            int cell = c0 + slot;
            if (cell < 81 && score_l[cell] == 0.0)
                fused_partial(cell, q, slot, H1, W2T, pbuf);
        }
        __syncthreads();
        if (t < 22) {
            int cell = c0 + t;
            if (cell < 81 && score_l[cell] == 0.0)
                combine_softmax(cell, t, pbuf, outp, score_l, pos_l);
        }
        __syncthreads();
    }

    // main loop: one fill per iteration
    for (; ne > 0; --ne) {
        // Phase R: argmax over 81 cached scores (first-index tie-break)
        if (t < 128) {
            double s; int i;
            if (t < 81) { s = score_l[t]; i = t; } else { s = -1.0; i = 127; }
#pragma unroll
            for (int off = 1; off < 64; off <<= 1) {
                double s2 = __shfl_xor(s, off);
                int    i2 = __shfl_xor(i, off);
                if (s2 > s || (s2 == s && i2 < i)) { s = s2; i = i2; }
            }
            if ((t & 63) == 0) { red_s[t >> 6] = s; red_i[t >> 6] = i; }
        }
        __syncthreads();
        // Phase A: t0 picks winner, applies fill + count updates
        if (t == 0) {
            double s1 = red_s[0]; int i1 = red_i[0];
            if (red_s[1] > s1) { s1 = red_s[1]; i1 = red_i[1]; }  // wave1 idx > wave0 idx on tie
            int cell = i1, bv = pos_l[cell];
            bc_cell = cell;
            xs[cell * 9 + bv] = 1.0f;
            score_l[cell] = -1.0;
            int r = cell / 9, c = cell - 9 * r;
            int bx = (r / 3) * 3 + c / 3;
            cnt[r * 12 + bv] += 1.f;
            cnt[(9 + c) * 12 + bv] += 1.f;
            cnt[(18 + bx) * 12 + bv] += 1.f;
        }
        __syncthreads();
        const int fcell = bc_cell;
        const int fr = fcell / 9, fc = fcell - 9 * fr;
        const int fbx = (fr / 3) * 3 + fc / 3;
        // Phase H: fresh H1 for the 3 affected groups (canonical v-order)
        for (int o = t; o < 300; o += TPB) {
            int gi = o / 100, j = o - 100 * gi;
            int g = (gi == 0) ? fr : (gi == 1) ? (9 + fc) : (18 + fbx);
            const float* w = W1 + j * 27 + gi * 9;
            const float* cc = cnt + g * 12;
            double s = 0.0;
#pragma unroll
            for (int v = 0; v < 9; v++) s = fma((double)w[v], (double)cc[v], s);
            H1[g * 101 + j] = s;
        }
        __syncthreads();
        // Phase F: recompute partials for affected empty cells (<=20)
        {
            int slot = t % 22, q = t / 22;
            if (q < 5) {
                int cell = affected_cell(slot, fr, fc);
                if (score_l[cell] >= 0.0)
                    fused_partial(cell, q, slot, H1, W2T, pbuf);
            }
        }
        __syncthreads();
        // Phase C: combine + softmax + cache/update
        if (t < 22) {
            int cell = affected_cell(t, fr, fc);
            if (score_l[cell] >= 0.0)
                combine_softmax(cell, t, pbuf, outp, score_l, pos_l);
        }
        __syncthreads();
    }

    for (int i = t; i < 729; i += TPB) outx[i] = xs[i];
}

extern "C" void kernel_launch(void* const* d_in, const int* in_sizes, int n_in,
                              void* d_out, int out_size, void* d_ws, size_t ws_size,
                              hipStream_t stream) {
    const float* x  = (const float*)d_in[0];
    const float* W1 = (const float*)d_in[1];
    const float* W2 = (const float*)d_in[2];
    int nb = in_sizes[0] / 729;
    (void)n_in; (void)out_size; (void)d_ws; (void)ws_size;
    sudoku_kernel<<<nb, TPB, 0, stream>>>(x, W1, W2, (float*)d_out, nb);
}

// Round 5
// 1278.546 us; speedup vs baseline: 3.4425x; 1.0316x over previous
//
#include <hip/hip_runtime.h>

#define TPB 256

// Decision-critical math (H1, hidden, y, softmax) is f64 with one fixed,
// canonical summation structure everywhere -> equal count-triples give
// bit-identical scores, so np first-index tie-breaks are reproduced by
// strict-> comparisons in index order. (Validated in R2/R3.)
//
// Affected set of one fill = 9 row cells + 9 col cells + 4 box cells
// outside the filled row/col = 22 slots. (R4 bug: used 20.)

__device__ __forceinline__ int affected_cell(int slot, int fr, int fc) {
    if (slot < 9)  return fr * 9 + slot;            // row cells
    if (slot < 18) return (slot - 9) * 9 + fc;      // col cells
    int r0 = (fr / 3) * 3, c0 = (fc / 3) * 3;       // box cells off-row/off-col
    int dr = fr - r0, dc = fc - c0;
    int rA = r0 + (dr == 0 ? 1 : 0), rB = r0 + (dr == 2 ? 1 : 2);
    int cA = c0 + (dc == 0 ? 1 : 0), cB = c0 + (dc == 2 ? 1 : 2);
    int k = slot - 18;
    return ((k < 2) ? rA : rB) * 9 + ((k & 1) ? cB : cA);
}

// F: partial y over j-chunk q (12 j's, last chunk 4). 22 slots x 9 chunks.
__device__ __forceinline__ void do_F(int slot, int q, int cell,
    const double* __restrict__ H1, const float* __restrict__ W2T,
    double* __restrict__ pbuf)
{
    int r = cell / 9, c = cell - 9 * r;
    int bx = (r / 3) * 3 + c / 3;
    const double* Hr = H1 + r * 101;
    const double* Hc = H1 + (9 + c) * 101;
    const double* Hb = H1 + (18 + bx) * 101;
    double acc[9];
#pragma unroll
    for (int v = 0; v < 9; v++) acc[v] = 0.0;
    const int j0 = q * 12;
#pragma unroll
    for (int jj = 0; jj < 12; jj++) {
        int j = j0 + jj;
        if (j < 100) {
            double h = Hr[j] + Hc[j] + Hb[j];
            h = h > 0.0 ? h : 0.0;
            const float* w = W2T + j * 12;
#pragma unroll
            for (int v = 0; v < 9; v++) acc[v] = fma(h, (double)w[v], acc[v]);
        }
    }
    double* pb = pbuf + (slot * 9 + q) * 9;
#pragma unroll
    for (int v = 0; v < 9; v++) pb[v] = acc[v];
}

// Wave-synchronous combine+softmax: a slot's 9 v-lanes live in ONE wave
// (lockstep, per-wave LDS ordering); wave_barrier fences the compiler.
__device__ __forceinline__ void do_C(int slot, int v, int cell,
    const double* __restrict__ pbuf, double* __restrict__ ybuf,
    double* __restrict__ pexp, float* __restrict__ xp,
    double* __restrict__ score_l, int* __restrict__ pos_l)
{
    double y = 0.0;
#pragma unroll
    for (int q = 0; q < 9; q++) y += pbuf[(slot * 9 + q) * 9 + v];
    ybuf[slot * 9 + v] = y;
    __builtin_amdgcn_wave_barrier();
    double m = ybuf[slot * 9 + 0];
#pragma unroll
    for (int v2 = 1; v2 < 9; v2++) m = fmax(m, ybuf[slot * 9 + v2]);
    pexp[slot * 9 + v] = exp(y - m);
    __builtin_amdgcn_wave_barrier();
    if (v == 0) {
        double sum = 0.0;
#pragma unroll
        for (int v2 = 0; v2 < 9; v2++) sum += pexp[slot * 9 + v2];
        double inv = 1.0 / sum;
        double best = -1.0; int bv = 0;
#pragma unroll
        for (int v2 = 0; v2 < 9; v2++) {
            double pr = pexp[slot * 9 + v2] * inv;
            xp[cell * 9 + v2] = (float)pr;
            if (pr > best) { best = pr; bv = v2; }  // strict > : first-index tie-break
        }
        score_l[cell] = best;
        pos_l[cell] = bv;
    }
}

__global__ __launch_bounds__(TPB, 4) void sudoku_kernel(
    const float* __restrict__ x_in,
    const float* __restrict__ W1,
    const float* __restrict__ W2,
    float* __restrict__ out,
    int nb)
{
    const int b = blockIdx.x;
    const int t = threadIdx.x;

    __shared__ float  xs[729];
    __shared__ float  xp[729];
    __shared__ float  W2T[100 * 12];   // W2T[j*12+v] = W2[v][j]
    __shared__ float  cnt[27 * 12];    // exact small ints
    __shared__ double H1[27 * 101];
    __shared__ double pbuf[22 * 9 * 9];  // [slot][q][v]
    __shared__ double ybuf[22 * 9];
    __shared__ double pexp[22 * 9];
    __shared__ double score_l[81];     // -1 = filled
    __shared__ int    pos_l[81];
    __shared__ int    bc_cell;

    const float* xb = x_in + (size_t)b * 729;
    for (int i = t; i < 729; i += TPB) { float v = xb[i]; xs[i] = v; xp[i] = v; }
    for (int i = t; i < 900; i += TPB) { int v = i / 100, j = i - 100 * v; W2T[j * 12 + v] = W2[i]; }
    __syncthreads();

    // empty flags + initial counts
    if (t < 81) {
        float s = 0.f;
#pragma unroll
        for (int v = 0; v < 9; v++) s += xs[t * 9 + v];
        score_l[t] = (s == 0.f) ? 0.0 : -1.0;
        pos_l[t] = 0;
    }
    for (int o = t; o < 243; o += TPB) {
        int g = o / 9, v = o - 9 * g;
        float s = 0.f;
        if (g < 9) {
            int base = g * 9;
#pragma unroll
            for (int k = 0; k < 9; k++) s += xs[(base + k) * 9 + v];
        } else if (g < 18) {
            int c = g - 9;
#pragma unroll
            for (int k = 0; k < 9; k++) s += xs[(c + 9 * k) * 9 + v];
        } else {
            int bx = g - 18;
            int base = (bx / 3) * 27 + (bx % 3) * 3;
#pragma unroll
            for (int k = 0; k < 9; k++) s += xs[(base + (k / 3) * 9 + (k % 3)) * 9 + v];
        }
        cnt[g * 12 + v] = s;
    }
    __syncthreads();

    // full H1 init (canonical v-order; W1 from global, L1-hot)
    for (int o = t; o < 2700; o += TPB) {
        int g = o / 100, j = o - 100 * g;
        int type = (g >= 18) ? 2 : (g >= 9 ? 1 : 0);
        const float* w = W1 + j * 27 + type * 9;
        const float* cc = cnt + g * 12;
        double s = 0.0;
#pragma unroll
        for (int v = 0; v < 9; v++) s = fma((double)w[v], (double)cc[v], s);
        H1[g * 101 + j] = s;
    }
    int myflag = (t < 81) ? (score_l[t] == 0.0) : 0;
    int ne = __syncthreads_count(myflag);

    // initial probs/scores for all empty cells, chunks of 22
    for (int c0 = 0; c0 < 81; c0 += 22) {
        if (t < 198) {
            int slot = t % 22, q = t / 22;
            int cell = c0 + slot;
            if (cell < 81 && score_l[cell] >= 0.0)
                do_F(slot, q, cell, H1, W2T, pbuf);
        }
        __syncthreads();
        {
            int w = t >> 6, l = t & 63;
            if (l < 63) {
                int sw = l / 9, v = l - 9 * sw;
                int slot = w * 7 + sw;
                int cell = c0 + slot;
                if (slot < 22 && cell < 81 && score_l[cell] >= 0.0)
                    do_C(slot, v, cell, pbuf, ybuf, pexp, xp, score_l, pos_l);
            }
        }
        __syncthreads();
    }

    // main loop: one fill per iteration
    for (int step = 0; step < ne; ++step) {
        // R+A fused on wave 0: butterfly argmax (all lanes get winner),
        // lane 0 applies fill + count updates.
        if (t < 64) {
            double s = score_l[t]; int idx = t;
            if (t < 17) {
                double s2 = score_l[64 + t];
                if (s2 > s) { s = s2; idx = 64 + t; }   // tie keeps lower idx
            }
#pragma unroll
            for (int off = 1; off < 64; off <<= 1) {
                double s2 = __shfl_xor(s, off);
                int    i2 = __shfl_xor(idx, off);
                if (s2 > s || (s2 == s && i2 < idx)) { s = s2; idx = i2; }
            }
            if (t == 0) {
                int cell = idx, bv = pos_l[cell];
                bc_cell = cell;
                xs[cell * 9 + bv] = 1.0f;
                score_l[cell] = -1.0;
                int r = cell / 9, c = cell - 9 * r;
                int bx = (r / 3) * 3 + c / 3;
                cnt[r * 12 + bv] += 1.f;
                cnt[(9 + c) * 12 + bv] += 1.f;
                cnt[(18 + bx) * 12 + bv] += 1.f;
            }
        }
        __syncthreads();
        const int fcell = bc_cell;
        const int fr = fcell / 9, fc = fcell - 9 * fr;
        const int fbx = (fr / 3) * 3 + fc / 3;

        // H: fresh H1 for the 3 affected groups (canonical v-order)
        for (int o = t; o < 300; o += TPB) {
            int gi = o / 100, j = o - 100 * gi;
            int g = (gi == 0) ? fr : (gi == 1) ? (9 + fc) : (18 + fbx);
            const float* w = W1 + j * 27 + gi * 9;
            const float* cc = cnt + g * 12;
            double s = 0.0;
#pragma unroll
            for (int v = 0; v < 9; v++) s = fma((double)w[v], (double)cc[v], s);
            H1[g * 101 + j] = s;
        }
        __syncthreads();

        // F: partial y for affected, still-empty cells (198 thr, 12 j each)
        if (t < 198) {
            int slot = t % 22, q = t / 22;
            int cell = affected_cell(slot, fr, fc);
            if (score_l[cell] >= 0.0)
                do_F(slot, q, cell, H1, W2T, pbuf);
        }
        __syncthreads();

        // C: combine + parallel softmax + cache/update (wave-sync, 4 waves x 7 slots)
        {
            int w = t >> 6, l = t & 63;
            if (l < 63) {
                int sw = l / 9, v = l - 9 * sw;
                int slot = w * 7 + sw;
                if (slot < 22) {
                    int cell = affected_cell(slot, fr, fc);
                    if (score_l[cell] >= 0.0)
                        do_C(slot, v, cell, pbuf, ybuf, pexp, xp, score_l, pos_l);
                }
            }
        }
        __syncthreads();
    }

    float* outp = out + (size_t)b * 729;
    float* outx = out + (size_t)nb * 729 + (size_t)b * 729;
    for (int i = t; i < 729; i += TPB) { outp[i] = xp[i]; outx[i] = xs[i]; }
}

extern "C" void kernel_launch(void* const* d_in, const int* in_sizes, int n_in,
                              void* d_out, int out_size, void* d_ws, size_t ws_size,
                              hipStream_t stream) {
    const float* x  = (const float*)d_in[0];
    const float* W1 = (const float*)d_in[1];
    const float* W2 = (const float*)d_in[2];
    int nb = in_sizes[0] / 729;
    (void)n_in; (void)out_size; (void)d_ws; (void)ws_size;
    sudoku_kernel<<<nb, TPB, 0, stream>>>(x, W1, W2, (float*)d_out, nb);
}